// Round 1
// baseline (972.897 us; speedup 1.0000x reference)
//
#include <hip/hip_runtime.h>
#include <cstdint>
#include <cstddef>

#define NEG_SLOPE 0.2f

__device__ __forceinline__ float leaky(float x){ return x > 0.f ? x : NEG_SLOPE * x; }
__device__ __forceinline__ float elu(float x){ return x > 0.f ? x : __expf(x) - 1.f; }

// ---------------- GEMM: C[m,n] = sum_k A[m*K+k] * B[n*K+k] ----------------
// A:[M,K] row-major, B:[N,K] row-major (i.e. C = A @ B^T). 64x64 tile, 256 thr, 4x4/thread.
template<int BK>
__global__ __launch_bounds__(256) void k_gemm_nt(const float* __restrict__ A,
                                                 const float* __restrict__ B,
                                                 float* __restrict__ C,
                                                 int M, int Nn, int K)
{
    __shared__ float As[BK * 65];
    __shared__ float Bs[BK * 65];
    const int tid = threadIdx.x;
    const int tx = tid & 15, ty = tid >> 4;
    const int m0 = blockIdx.x * 64, n0 = blockIdx.y * 64;
    float acc[4][4] = {};

    constexpr int ROWF4 = BK / 4;       // float4 per row
    constexpr int NSLOT = 64 * ROWF4;   // float4 slots per tile

    for (int k0 = 0; k0 < K; k0 += BK) {
        for (int f = tid; f < NSLOT; f += 256) {
            int row = f / ROWF4, c4 = f % ROWF4;
            int rg = m0 + row;
            float4 va = make_float4(0.f, 0.f, 0.f, 0.f);
            if (rg < M) va = *(const float4*)(A + (size_t)rg * K + k0 + c4 * 4);
            As[(c4*4+0)*65 + row] = va.x;
            As[(c4*4+1)*65 + row] = va.y;
            As[(c4*4+2)*65 + row] = va.z;
            As[(c4*4+3)*65 + row] = va.w;
            int ng = n0 + row;   // Nn % 64 == 0, always in range
            float4 vb = *(const float4*)(B + (size_t)ng * K + k0 + c4 * 4);
            Bs[(c4*4+0)*65 + row] = vb.x;
            Bs[(c4*4+1)*65 + row] = vb.y;
            Bs[(c4*4+2)*65 + row] = vb.z;
            Bs[(c4*4+3)*65 + row] = vb.w;
        }
        __syncthreads();
        #pragma unroll
        for (int k = 0; k < BK; ++k) {
            float a[4], b[4];
            #pragma unroll
            for (int i = 0; i < 4; ++i) a[i] = As[k*65 + tx*4 + i];
            #pragma unroll
            for (int j = 0; j < 4; ++j) b[j] = Bs[k*65 + ty*4 + j];
            #pragma unroll
            for (int i = 0; i < 4; ++i)
                #pragma unroll
                for (int j = 0; j < 4; ++j)
                    acc[i][j] += a[i] * b[j];
        }
        __syncthreads();
    }
    #pragma unroll
    for (int i = 0; i < 4; ++i) {
        int m = m0 + tx*4 + i;
        if (m < M) {
            float4 o = make_float4(acc[i][0], acc[i][1], acc[i][2], acc[i][3]);
            *(float4*)(C + (size_t)m * Nn + n0 + ty*4) = o;
        }
    }
}

// ---------------- attention coefficients, layer 1 (H=4, C=128) ----------------
__global__ __launch_bounds__(256) void k_attn1(const float* __restrict__ xh,
                                               const float* __restrict__ as1,
                                               const float* __restrict__ ad1,
                                               float* __restrict__ a_s,
                                               float* __restrict__ a_d, int N)
{
    int n = blockIdx.x;
    int lane = threadIdx.x & 63, h = threadIdx.x >> 6;
    float2 xv = *(const float2*)(xh + (size_t)n*512 + h*128 + lane*2);
    float2 sv = *(const float2*)(as1 + h*128 + lane*2);
    float2 dv = *(const float2*)(ad1 + h*128 + lane*2);
    float ps = xv.x*sv.x + xv.y*sv.y;
    float pd = xv.x*dv.x + xv.y*dv.y;
    for (int off = 32; off; off >>= 1) { ps += __shfl_xor(ps, off); pd += __shfl_xor(pd, off); }
    if (lane == 0) { a_s[n*4+h] = ps; a_d[n*4+h] = pd; }
}

// ---------------- attention coefficients, layer 2 (H=1, C=128) ----------------
__global__ __launch_bounds__(256) void k_attn2(const float* __restrict__ xh,
                                               const float* __restrict__ as2,
                                               const float* __restrict__ ad2,
                                               float* __restrict__ a_s,
                                               float* __restrict__ a_d, int N)
{
    int n = blockIdx.x*4 + (threadIdx.x >> 6);
    if (n >= N) return;
    int lane = threadIdx.x & 63;
    float2 xv = *(const float2*)(xh + (size_t)n*128 + lane*2);
    float2 sv = *(const float2*)(as2 + lane*2);
    float2 dv = *(const float2*)(ad2 + lane*2);
    float ps = xv.x*sv.x + xv.y*sv.y;
    float pd = xv.x*dv.x + xv.y*dv.y;
    for (int off = 32; off; off >>= 1) { ps += __shfl_xor(ps, off); pd += __shfl_xor(pd, off); }
    if (lane == 0) { a_s[n] = ps; a_d[n] = pd; }
}

// ---------------- CSR construction ----------------
__global__ void k_count(const int* __restrict__ ei, int* __restrict__ deg, int E, int Ep)
{
    int e = blockIdx.x * blockDim.x + threadIdx.x;
    if (e >= Ep) return;
    int dst = (e < E) ? ei[E + e] : (e - E);
    atomicAdd(&deg[dst], 1);
}

__global__ __launch_bounds__(1024) void k_scanA(const int* __restrict__ deg,
                                                int* __restrict__ start,
                                                int* __restrict__ sums, int Ntot, int N)
{
    __shared__ int sm[1024];
    int tid = threadIdx.x;
    int i = blockIdx.x * 1024 + tid;
    int v = (i < N) ? deg[i] : 0;
    sm[tid] = v; __syncthreads();
    for (int off = 1; off < 1024; off <<= 1) {
        int t = (tid >= off) ? sm[tid - off] : 0;
        __syncthreads();
        sm[tid] += t;
        __syncthreads();
    }
    if (i < Ntot) start[i] = sm[tid] - v;       // exclusive
    if (tid == 1023) sums[blockIdx.x] = sm[1023];
}

__global__ void k_scanB(int* sums, int nb)      // nb <= 64 (N=50000 -> nb=49)
{
    int l = threadIdx.x;
    int v = (l < nb) ? sums[l] : 0;
    int orig = v;
    for (int off = 1; off < 64; off <<= 1) { int t = __shfl_up(v, off); if (l >= off) v += t; }
    if (l < nb) sums[l] = v - orig;             // exclusive over blocks
}

__global__ __launch_bounds__(1024) void k_scanC(int* __restrict__ start,
                                                const int* __restrict__ sums, int Ntot)
{
    int i = blockIdx.x * 1024 + threadIdx.x;
    if (i < Ntot) start[i] += sums[blockIdx.x];
}

__global__ void k_fill(const int* __restrict__ ei, const int* __restrict__ start,
                       int* __restrict__ cursor, int* __restrict__ csr_src, int E, int Ep)
{
    int e = blockIdx.x * blockDim.x + threadIdx.x;
    if (e >= Ep) return;
    int src, dst;
    if (e < E) { src = ei[e]; dst = ei[E + e]; } else { src = dst = e - E; }
    int pos = atomicAdd(&cursor[dst], 1);
    csr_src[start[dst] + pos] = src;
}

// ---------------- layer-1 aggregation: softmax + gather + bias + ELU ----------------
#define CAP1 768
__global__ __launch_bounds__(256) void k_agg1(const int* __restrict__ start,
                                              const int* __restrict__ csr_src,
                                              const float* __restrict__ a_s,
                                              const float* __restrict__ a_d,
                                              const float* __restrict__ xh,
                                              const float* __restrict__ b1,
                                              float* __restrict__ h1, int N)
{
    int d = blockIdx.x, tid = threadIdx.x;
    __shared__ float s_alpha[CAP1 * 4];
    __shared__ int   s_src[CAP1];
    __shared__ float red[4 * 256];
    __shared__ float s_inv[4];

    int beg = start[d], end = start[d + 1];
    int deg = end - beg;
    float ad0 = a_d[d*4+0], ad1v = a_d[d*4+1], ad2v = a_d[d*4+2], ad3v = a_d[d*4+3];

    float ps0 = 0, ps1 = 0, ps2 = 0, ps3 = 0;
    for (int i = tid; i < deg; i += 256) {
        int s = csr_src[beg + i];
        const float* asr = a_s + (size_t)s * 4;
        float e0 = __expf(leaky(asr[0] + ad0));
        float e1 = __expf(leaky(asr[1] + ad1v));
        float e2 = __expf(leaky(asr[2] + ad2v));
        float e3 = __expf(leaky(asr[3] + ad3v));
        ps0 += e0; ps1 += e1; ps2 += e2; ps3 += e3;
        if (i < CAP1) { s_src[i] = s; *(float4*)&s_alpha[i*4] = make_float4(e0, e1, e2, e3); }
    }
    red[tid] = ps0; red[256+tid] = ps1; red[512+tid] = ps2; red[768+tid] = ps3;
    __syncthreads();
    for (int st = 128; st > 0; st >>= 1) {
        if (tid < st) {
            red[tid]     += red[tid+st];
            red[256+tid] += red[256+tid+st];
            red[512+tid] += red[512+tid+st];
            red[768+tid] += red[768+tid+st];
        }
        __syncthreads();
    }
    if (tid < 4) s_inv[tid] = 1.f / (red[tid*256] + 1e-16f);
    __syncthreads();
    int ncap = deg < CAP1 ? deg : CAP1;
    for (int j = tid; j < ncap*4; j += 256) s_alpha[j] *= s_inv[j & 3];
    __syncthreads();

    int h = tid >> 6;               // c = 2*tid; head = c/128 = tid/64 (wave-uniform)
    float invh = s_inv[h];
    float adh = (h == 0) ? ad0 : (h == 1) ? ad1v : (h == 2) ? ad2v : ad3v;
    int c = tid * 2;
    const float* xcol = xh + c;
    float accx = 0.f, accy = 0.f;
    for (int i = 0; i < deg; ++i) {
        float al; int s;
        if (i < CAP1) { al = s_alpha[i*4 + h]; s = s_src[i]; }
        else { s = csr_src[beg + i]; al = __expf(leaky(a_s[(size_t)s*4 + h] + adh)) * invh; }
        float2 v = *(const float2*)(xcol + (size_t)s * 512);
        accx += al * v.x; accy += al * v.y;
    }
    float2 bb = *(const float2*)(b1 + c);
    float ox = elu(accx + bb.x), oy = elu(accy + bb.y);
    *(float2*)(h1 + (size_t)d * 512 + c) = make_float2(ox, oy);
}

// ---------------- layer-2 aggregation + ELU + fused mean-pool accumulation ----------------
#define CAP2 768
__global__ __launch_bounds__(128) void k_agg2(const int* __restrict__ start,
                                              const int* __restrict__ csr_src,
                                              const float* __restrict__ a_s,
                                              const float* __restrict__ a_d,
                                              const float* __restrict__ xh2,
                                              const float* __restrict__ b2,
                                              const int* __restrict__ batch,
                                              float* __restrict__ pooled, int N)
{
    int d = blockIdx.x, tid = threadIdx.x;
    __shared__ float s_alpha[CAP2];
    __shared__ int   s_src[CAP2];
    __shared__ float red[128];
    __shared__ float s_invs;

    int beg = start[d], end = start[d + 1];
    int deg = end - beg;
    float ad = a_d[d];
    float ps = 0.f;
    for (int i = tid; i < deg; i += 128) {
        int s = csr_src[beg + i];
        float e = __expf(leaky(a_s[s] + ad));
        ps += e;
        if (i < CAP2) { s_src[i] = s; s_alpha[i] = e; }
    }
    red[tid] = ps; __syncthreads();
    for (int st = 64; st > 0; st >>= 1) { if (tid < st) red[tid] += red[tid+st]; __syncthreads(); }
    if (tid == 0) s_invs = 1.f / (red[0] + 1e-16f);
    __syncthreads();
    float inv = s_invs;
    float acc = 0.f;
    for (int i = 0; i < deg; ++i) {
        float al; int s;
        if (i < CAP2) { al = s_alpha[i] * inv; s = s_src[i]; }
        else { s = csr_src[beg + i]; al = __expf(leaky(a_s[s] + ad)) * inv; }
        acc += al * xh2[(size_t)s * 128 + tid];
    }
    float val = elu(acc + b2[tid]);
    atomicAdd(&pooled[(size_t)batch[d] * 128 + tid], val);
}

__global__ void k_cnt(const int* __restrict__ batch, int* __restrict__ cnt, int N)
{
    int n = blockIdx.x * blockDim.x + threadIdx.x;
    if (n < N) atomicAdd(&cnt[batch[n]], 1);
}

// ---------------- final: mean + relu(pooled@Wh1^T+bh1) @ Wh2^T + bh2 ----------------
__global__ __launch_bounds__(128) void k_final(const float* __restrict__ pooled,
                                               const int* __restrict__ cnt,
                                               const float* __restrict__ Wh1,
                                               const float* __restrict__ bh1,
                                               const float* __restrict__ Wh2,
                                               const float* __restrict__ bh2,
                                               float* __restrict__ out)
{
    int g = blockIdx.x, c = threadIdx.x;
    __shared__ float p[128];
    __shared__ float red[128];
    float cf = (float)cnt[g]; cf = cf > 1.f ? cf : 1.f;
    p[c] = pooled[(size_t)g*128 + c] / cf;
    __syncthreads();
    float z = bh1[c];
    for (int k = 0; k < 128; ++k) z += p[k] * Wh1[c*128 + k];
    z = z > 0.f ? z : 0.f;
    red[c] = z * Wh2[c];
    __syncthreads();
    for (int st = 64; st > 0; st >>= 1) { if (c < st) red[c] += red[c+st]; __syncthreads(); }
    if (c == 0) out[g] = red[0] + bh2[0];
}

// ---------------- launch ----------------
extern "C" void kernel_launch(void* const* d_in, const int* in_sizes, int n_in,
                              void* d_out, int out_size, void* d_ws, size_t ws_size,
                              hipStream_t stream)
{
    const float* x   = (const float*)d_in[0];
    const int*   ei  = (const int*)d_in[1];
    const int*   bat = (const int*)d_in[2];
    const float* W1  = (const float*)d_in[3];
    const float* as1 = (const float*)d_in[4];
    const float* ad1 = (const float*)d_in[5];
    const float* b1  = (const float*)d_in[6];
    const float* W2  = (const float*)d_in[7];
    const float* as2 = (const float*)d_in[8];
    const float* ad2 = (const float*)d_in[9];
    const float* b2  = (const float*)d_in[10];
    const float* Wh1 = (const float*)d_in[11];
    const float* bh1 = (const float*)d_in[12];
    const float* Wh2 = (const float*)d_in[13];
    const float* bh2 = (const float*)d_in[14];
    float* out = (float*)d_out;

    const int N  = in_sizes[0] / 128;
    const int E  = in_sizes[1] / 2;
    const int Ep = E + N;
    const int G  = 128;

    char* w = (char*)d_ws;
    size_t off = 0;
    auto alloc = [&](size_t bytes) -> char* {
        char* p = w + off; off += (bytes + 511) & ~(size_t)511; return p;
    };
    float* xh1   = (float*)alloc((size_t)N * 512 * 4);   // reused as xh2 after agg1
    float* h1    = (float*)alloc((size_t)N * 512 * 4);
    float* As1   = (float*)alloc((size_t)N * 4 * 4);
    float* Ad1   = (float*)alloc((size_t)N * 4 * 4);
    float* As2   = (float*)alloc((size_t)N * 4);
    float* Ad2   = (float*)alloc((size_t)N * 4);
    int*   startb= (int*)alloc((size_t)(N + 1) * 4);
    int*   csr   = (int*)alloc((size_t)Ep * 4);
    int*   sums  = (int*)alloc(4096);
    char* zbase = w + off;                                // zero-init group
    int*   deg    = (int*)alloc((size_t)N * 4);
    int*   cursor = (int*)alloc((size_t)N * 4);
    float* pooled = (float*)alloc((size_t)G * 128 * 4);
    int*   cnt    = (int*)alloc((size_t)G * 4);
    size_t zbytes = (size_t)((w + off) - zbase);
    float* xh2 = xh1;   // xh1 dead after k_agg1 (stream-ordered)

    hipMemsetAsync(zbase, 0, zbytes, stream);

    // 1) xh1 = x @ W1^T   [N,512]
    dim3 g1((N + 63) / 64, 512 / 64);
    k_gemm_nt<32><<<g1, dim3(256), 0, stream>>>(x, W1, xh1, N, 512, 128);
    // 2) per-node attention coefficients, layer 1
    k_attn1<<<N, 256, 0, stream>>>(xh1, as1, ad1, As1, Ad1, N);
    // 3) CSR by destination (self-loops appended)
    k_count<<<(Ep + 255) / 256, 256, 0, stream>>>(ei, deg, E, Ep);
    int nb = (N + 1 + 1023) / 1024;
    k_scanA<<<nb, 1024, 0, stream>>>(deg, startb, sums, N + 1, N);
    k_scanB<<<1, 64, 0, stream>>>(sums, nb);
    k_scanC<<<nb, 1024, 0, stream>>>(startb, sums, N + 1);
    k_fill<<<(Ep + 255) / 256, 256, 0, stream>>>(ei, startb, cursor, csr, E, Ep);
    // 4) layer-1 aggregation (+bias+ELU)  -> h1 [N,512]
    k_agg1<<<N, 256, 0, stream>>>(startb, csr, As1, Ad1, xh1, b1, h1, N);
    // 5) xh2 = h1 @ W2^T   [N,128]
    dim3 g2((N + 63) / 64, 128 / 64);
    k_gemm_nt<32><<<g2, dim3(256), 0, stream>>>(h1, W2, xh2, N, 128, 512);
    // 6) attention coefficients, layer 2
    k_attn2<<<(N + 3) / 4, 256, 0, stream>>>(xh2, as2, ad2, As2, Ad2, N);
    // 7) node counts per graph
    k_cnt<<<(N + 255) / 256, 256, 0, stream>>>(bat, cnt, N);
    // 8) layer-2 aggregation (+bias+ELU) fused with mean-pool accumulation
    k_agg2<<<N, 128, 0, stream>>>(startb, csr, As2, Ad2, xh2, b2, bat, pooled, N);
    // 9) pooled mean + MLP head -> out [G]
    k_final<<<G, 128, 0, stream>>>(pooled, cnt, Wh1, bh1, Wh2, bh2, out);
}

// Round 2
// 724.041 us; speedup vs baseline: 1.3437x; 1.3437x over previous
//
#include <hip/hip_runtime.h>
#include <cstdint>
#include <cstddef>

#define NEG_SLOPE 0.2f

__device__ __forceinline__ float leaky(float x){ return x > 0.f ? x : NEG_SLOPE * x; }
__device__ __forceinline__ float elu(float x){ return x > 0.f ? x : __expf(x) - 1.f; }

// ============ big-tile GEMM: C[m,n] = sum_k A[m,k]*B[n,k]  (n-tile fixed at 128) ============
// block 256 threads, tile (TM*16) x 128, BK=16, per-thread TM x 8.
// z-dim indexes independent sub-GEMMs (heads) via aZ/bZ/cZ/biasZ element offsets.
template<int TM, bool FUSE_BIAS_ELU>
__global__ __launch_bounds__(256) void k_gemm_big(const float* __restrict__ A,
                                                  const float* __restrict__ B,
                                                  const float* __restrict__ bias,
                                                  float* __restrict__ C,
                                                  int M, int K, int lda, int ldb, int ldc,
                                                  long aZ, long bZ, long cZ, long biasZ)
{
    constexpr int TMROWS = TM * 16;
    constexpr int APAD = TMROWS + 4;
    constexpr int BPAD = 132;
    __shared__ float As[16 * APAD];
    __shared__ float Bs[16 * BPAD];

    const float* Ab = A + (size_t)blockIdx.z * aZ;
    const float* Bb = B + (size_t)blockIdx.z * bZ;
    float* Cb = C + (size_t)blockIdx.z * cZ;

    const int tid = threadIdx.x;
    const int tx = tid & 15, ty = tid >> 4;
    const int m0 = blockIdx.x * TMROWS;

    float acc[TM][8] = {};

    for (int k0 = 0; k0 < K; k0 += 16) {
        #pragma unroll
        for (int f = tid; f < TM * 64; f += 256) {
            int row = f >> 2, kq = f & 3;
            int rg = m0 + row;
            float4 v = make_float4(0.f, 0.f, 0.f, 0.f);
            if (rg < M) v = *(const float4*)(Ab + (size_t)rg * lda + k0 + kq * 4);
            As[(kq*4+0)*APAD + row] = v.x;
            As[(kq*4+1)*APAD + row] = v.y;
            As[(kq*4+2)*APAD + row] = v.z;
            As[(kq*4+3)*APAD + row] = v.w;
        }
        #pragma unroll
        for (int f = tid; f < 512; f += 256) {
            int row = f >> 2, kq = f & 3;
            float4 v = *(const float4*)(Bb + (size_t)row * ldb + k0 + kq * 4);
            Bs[(kq*4+0)*BPAD + row] = v.x;
            Bs[(kq*4+1)*BPAD + row] = v.y;
            Bs[(kq*4+2)*BPAD + row] = v.z;
            Bs[(kq*4+3)*BPAD + row] = v.w;
        }
        __syncthreads();
        #pragma unroll
        for (int k = 0; k < 16; ++k) {
            float a[TM], b[8];
            #pragma unroll
            for (int q = 0; q < TM/4; ++q)
                *(float4*)&a[q*4] = *(const float4*)&As[k*APAD + tx*TM + q*4];
            *(float4*)&b[0] = *(const float4*)&Bs[k*BPAD + ty*8];
            *(float4*)&b[4] = *(const float4*)&Bs[k*BPAD + ty*8 + 4];
            #pragma unroll
            for (int i = 0; i < TM; ++i)
                #pragma unroll
                for (int j = 0; j < 8; ++j)
                    acc[i][j] += a[i] * b[j];
        }
        __syncthreads();
    }
    #pragma unroll
    for (int i = 0; i < TM; ++i) {
        int m = m0 + tx*TM + i;
        if (m >= M) continue;
        float o[8];
        #pragma unroll
        for (int j = 0; j < 8; ++j) {
            float v = acc[i][j];
            if (FUSE_BIAS_ELU) {
                v += bias[blockIdx.z * biasZ + ty*8 + j];
                v = elu(v);
            }
            o[j] = v;
        }
        *(float4*)(Cb + (size_t)m * ldc + ty*8)     = *(float4*)&o[0];
        *(float4*)(Cb + (size_t)m * ldc + ty*8 + 4) = *(float4*)&o[4];
    }
}

// ============ fold attention vectors: w_s[h,k] = sum_c att_src[h,c] * W1[h*128+c, k] ============
__global__ __launch_bounds__(128) void k_wvec(const float* __restrict__ W1,
                                              const float* __restrict__ as1,
                                              const float* __restrict__ ad1,
                                              float* __restrict__ w_s,
                                              float* __restrict__ w_d)
{
    int h = blockIdx.x, k = threadIdx.x;
    float s = 0.f, d = 0.f;
    for (int c = 0; c < 128; ++c) {
        float w = W1[((size_t)(h*128 + c))*128 + k];
        s += as1[h*128 + c] * w;
        d += ad1[h*128 + c] * w;
    }
    w_s[h*128 + k] = s;
    w_d[h*128 + k] = d;
}

// ============ layer-1 attention logits from raw x:  a_s[n,h] = x[n] . w_s[h] ============
__global__ __launch_bounds__(256) void k_attn_x(const float* __restrict__ x,
                                                const float* __restrict__ w_s,
                                                const float* __restrict__ w_d,
                                                float* __restrict__ a_s,
                                                float* __restrict__ a_d, int N)
{
    int n = blockIdx.x*4 + (threadIdx.x >> 6);
    if (n >= N) return;
    int lane = threadIdx.x & 63;
    float2 xv = *(const float2*)(x + (size_t)n*128 + lane*2);
    float ps[4], pd[4];
    #pragma unroll
    for (int h = 0; h < 4; ++h) {
        float2 sv = *(const float2*)(w_s + h*128 + lane*2);
        float2 dv = *(const float2*)(w_d + h*128 + lane*2);
        ps[h] = xv.x*sv.x + xv.y*sv.y;
        pd[h] = xv.x*dv.x + xv.y*dv.y;
    }
    #pragma unroll
    for (int h = 0; h < 4; ++h)
        for (int off = 32; off; off >>= 1) {
            ps[h] += __shfl_xor(ps[h], off);
            pd[h] += __shfl_xor(pd[h], off);
        }
    if (lane == 0) {
        *(float4*)(a_s + (size_t)n*4) = make_float4(ps[0], ps[1], ps[2], ps[3]);
        *(float4*)(a_d + (size_t)n*4) = make_float4(pd[0], pd[1], pd[2], pd[3]);
    }
}

// ============ layer-2 attention logits (H=1, C=128) ============
__global__ __launch_bounds__(256) void k_attn2(const float* __restrict__ xh,
                                               const float* __restrict__ as2,
                                               const float* __restrict__ ad2,
                                               float* __restrict__ a_s,
                                               float* __restrict__ a_d, int N)
{
    int n = blockIdx.x*4 + (threadIdx.x >> 6);
    if (n >= N) return;
    int lane = threadIdx.x & 63;
    float2 xv = *(const float2*)(xh + (size_t)n*128 + lane*2);
    float2 sv = *(const float2*)(as2 + lane*2);
    float2 dv = *(const float2*)(ad2 + lane*2);
    float ps = xv.x*sv.x + xv.y*sv.y;
    float pd = xv.x*dv.x + xv.y*dv.y;
    for (int off = 32; off; off >>= 1) { ps += __shfl_xor(ps, off); pd += __shfl_xor(pd, off); }
    if (lane == 0) { a_s[n] = ps; a_d[n] = pd; }
}

// ============ CSR construction ============
__global__ void k_count(const int* __restrict__ ei, int* __restrict__ deg, int E, int Ep)
{
    int e = blockIdx.x * blockDim.x + threadIdx.x;
    if (e >= Ep) return;
    int dst = (e < E) ? ei[E + e] : (e - E);
    atomicAdd(&deg[dst], 1);
}

__global__ __launch_bounds__(1024) void k_scanA(const int* __restrict__ deg,
                                                int* __restrict__ start,
                                                int* __restrict__ sums, int Ntot, int N)
{
    __shared__ int sm[1024];
    int tid = threadIdx.x;
    int i = blockIdx.x * 1024 + tid;
    int v = (i < N) ? deg[i] : 0;
    sm[tid] = v; __syncthreads();
    for (int off = 1; off < 1024; off <<= 1) {
        int t = (tid >= off) ? sm[tid - off] : 0;
        __syncthreads();
        sm[tid] += t;
        __syncthreads();
    }
    if (i < Ntot) start[i] = sm[tid] - v;
    if (tid == 1023) sums[blockIdx.x] = sm[1023];
}

__global__ void k_scanB(int* sums, int nb)
{
    int l = threadIdx.x;
    int v = (l < nb) ? sums[l] : 0;
    int orig = v;
    for (int off = 1; off < 64; off <<= 1) { int t = __shfl_up(v, off); if (l >= off) v += t; }
    if (l < nb) sums[l] = v - orig;
}

__global__ __launch_bounds__(1024) void k_scanC(int* __restrict__ start,
                                                const int* __restrict__ sums, int Ntot)
{
    int i = blockIdx.x * 1024 + threadIdx.x;
    if (i < Ntot) start[i] += sums[blockIdx.x];
}

__global__ void k_fill(const int* __restrict__ ei, const int* __restrict__ start,
                       int* __restrict__ cursor, int* __restrict__ csr_src, int E, int Ep)
{
    int e = blockIdx.x * blockDim.x + threadIdx.x;
    if (e >= Ep) return;
    int src, dst;
    if (e < E) { src = ei[e]; dst = ei[E + e]; } else { src = dst = e - E; }
    int pos = atomicAdd(&cursor[dst], 1);
    csr_src[start[dst] + pos] = src;
}

// ============ layer-1 aggregation over RAW x (128-dim), 4 heads per pass ============
// agg[d, h*128+c] = sum_e alpha[e,h] * x[src_e, c]
#define CAPA 256
__global__ __launch_bounds__(128) void k_agg1x(const int* __restrict__ start,
                                               const int* __restrict__ csr_src,
                                               const float* __restrict__ a_s,
                                               const float* __restrict__ a_d,
                                               const float* __restrict__ x,
                                               float* __restrict__ agg, int N)
{
    int d = blockIdx.x, tid = threadIdx.x;
    __shared__ float s_al[CAPA * 4];
    __shared__ int   s_src[CAPA];
    __shared__ float red[4 * 128];
    __shared__ float s_inv[4];

    int beg = start[d], end = start[d + 1];
    int deg = end - beg;
    float4 ad4 = *(const float4*)(a_d + (size_t)d * 4);

    float ps0 = 0, ps1 = 0, ps2 = 0, ps3 = 0;
    for (int i = tid; i < deg; i += 128) {
        int s = csr_src[beg + i];
        float4 as4 = *(const float4*)(a_s + (size_t)s * 4);
        float e0 = __expf(leaky(as4.x + ad4.x));
        float e1 = __expf(leaky(as4.y + ad4.y));
        float e2 = __expf(leaky(as4.z + ad4.z));
        float e3 = __expf(leaky(as4.w + ad4.w));
        ps0 += e0; ps1 += e1; ps2 += e2; ps3 += e3;
        if (i < CAPA) { s_src[i] = s; *(float4*)&s_al[i*4] = make_float4(e0, e1, e2, e3); }
    }
    red[tid] = ps0; red[128+tid] = ps1; red[256+tid] = ps2; red[384+tid] = ps3;
    __syncthreads();
    for (int st = 64; st > 0; st >>= 1) {
        if (tid < st) {
            red[tid]     += red[tid+st];
            red[128+tid] += red[128+tid+st];
            red[256+tid] += red[256+tid+st];
            red[384+tid] += red[384+tid+st];
        }
        __syncthreads();
    }
    if (tid < 4) s_inv[tid] = 1.f / (red[tid*128] + 1e-16f);
    __syncthreads();
    int ncap4 = (deg < CAPA ? deg : CAPA) * 4;
    for (int j = tid; j < ncap4; j += 128) s_al[j] *= s_inv[j & 3];
    __syncthreads();

    float inv0 = s_inv[0], inv1 = s_inv[1], inv2 = s_inv[2], inv3 = s_inv[3];
    int c = tid;
    float acc0 = 0.f, acc1 = 0.f, acc2 = 0.f, acc3 = 0.f;
    for (int i = 0; i < deg; ++i) {
        float4 al; int s;
        if (i < CAPA) { al = *(const float4*)&s_al[i*4]; s = s_src[i]; }
        else {
            s = csr_src[beg + i];
            float4 as4 = *(const float4*)(a_s + (size_t)s * 4);
            al.x = __expf(leaky(as4.x + ad4.x)) * inv0;
            al.y = __expf(leaky(as4.y + ad4.y)) * inv1;
            al.z = __expf(leaky(as4.z + ad4.z)) * inv2;
            al.w = __expf(leaky(as4.w + ad4.w)) * inv3;
        }
        float xv = x[(size_t)s * 128 + c];
        acc0 += al.x * xv; acc1 += al.y * xv; acc2 += al.z * xv; acc3 += al.w * xv;
    }
    float* o = agg + (size_t)d * 512 + c;
    o[0]   = acc0;
    o[128] = acc1;
    o[256] = acc2;
    o[384] = acc3;
}

// ============ layer-2 aggregation + bias + ELU + fused mean-pool accumulation ============
#define CAP2 256
__global__ __launch_bounds__(128) void k_agg2(const int* __restrict__ start,
                                              const int* __restrict__ csr_src,
                                              const float* __restrict__ a_s,
                                              const float* __restrict__ a_d,
                                              const float* __restrict__ xh2,
                                              const float* __restrict__ b2,
                                              const int* __restrict__ batch,
                                              float* __restrict__ pooled, int N)
{
    int d = blockIdx.x, tid = threadIdx.x;
    __shared__ float s_alpha[CAP2];
    __shared__ int   s_src[CAP2];
    __shared__ float red[128];
    __shared__ float s_invs;

    int beg = start[d], end = start[d + 1];
    int deg = end - beg;
    float ad = a_d[d];
    float ps = 0.f;
    for (int i = tid; i < deg; i += 128) {
        int s = csr_src[beg + i];
        float e = __expf(leaky(a_s[s] + ad));
        ps += e;
        if (i < CAP2) { s_src[i] = s; s_alpha[i] = e; }
    }
    red[tid] = ps; __syncthreads();
    for (int st = 64; st > 0; st >>= 1) { if (tid < st) red[tid] += red[tid+st]; __syncthreads(); }
    if (tid == 0) s_invs = 1.f / (red[0] + 1e-16f);
    __syncthreads();
    float inv = s_invs;
    float acc = 0.f;
    for (int i = 0; i < deg; ++i) {
        float al; int s;
        if (i < CAP2) { al = s_alpha[i] * inv; s = s_src[i]; }
        else { s = csr_src[beg + i]; al = __expf(leaky(a_s[s] + ad)) * inv; }
        acc += al * xh2[(size_t)s * 128 + tid];
    }
    float val = elu(acc + b2[tid]);
    atomicAdd(&pooled[(size_t)batch[d] * 128 + tid], val);
}

__global__ void k_cnt(const int* __restrict__ batch, int* __restrict__ cnt, int N)
{
    int n = blockIdx.x * blockDim.x + threadIdx.x;
    if (n < N) atomicAdd(&cnt[batch[n]], 1);
}

// ============ final: mean + relu(pooled@Wh1^T+bh1) @ Wh2^T + bh2 ============
__global__ __launch_bounds__(128) void k_final(const float* __restrict__ pooled,
                                               const int* __restrict__ cnt,
                                               const float* __restrict__ Wh1,
                                               const float* __restrict__ bh1,
                                               const float* __restrict__ Wh2,
                                               const float* __restrict__ bh2,
                                               float* __restrict__ out)
{
    int g = blockIdx.x, c = threadIdx.x;
    __shared__ float p[128];
    __shared__ float red[128];
    float cf = (float)cnt[g]; cf = cf > 1.f ? cf : 1.f;
    p[c] = pooled[(size_t)g*128 + c] / cf;
    __syncthreads();
    float z = bh1[c];
    for (int k = 0; k < 128; ++k) z += p[k] * Wh1[c*128 + k];
    z = z > 0.f ? z : 0.f;
    red[c] = z * Wh2[c];
    __syncthreads();
    for (int st = 64; st > 0; st >>= 1) { if (c < st) red[c] += red[c+st]; __syncthreads(); }
    if (c == 0) out[g] = red[0] + bh2[0];
}

// ============ launch ============
extern "C" void kernel_launch(void* const* d_in, const int* in_sizes, int n_in,
                              void* d_out, int out_size, void* d_ws, size_t ws_size,
                              hipStream_t stream)
{
    const float* x   = (const float*)d_in[0];
    const int*   ei  = (const int*)d_in[1];
    const int*   bat = (const int*)d_in[2];
    const float* W1  = (const float*)d_in[3];
    const float* as1 = (const float*)d_in[4];
    const float* ad1 = (const float*)d_in[5];
    const float* b1  = (const float*)d_in[6];
    const float* W2  = (const float*)d_in[7];
    const float* as2 = (const float*)d_in[8];
    const float* ad2 = (const float*)d_in[9];
    const float* b2  = (const float*)d_in[10];
    const float* Wh1 = (const float*)d_in[11];
    const float* bh1 = (const float*)d_in[12];
    const float* Wh2 = (const float*)d_in[13];
    const float* bh2 = (const float*)d_in[14];
    float* out = (float*)d_out;

    const int N  = in_sizes[0] / 128;
    const int E  = in_sizes[1] / 2;
    const int Ep = E + N;
    const int G  = 128;

    char* w = (char*)d_ws;
    size_t off = 0;
    auto alloc = [&](size_t bytes) -> char* {
        char* p = w + off; off += (bytes + 511) & ~(size_t)511; return p;
    };
    float* agg   = (float*)alloc((size_t)N * 512 * 4);   // layer-1 per-head aggregated x; reused as xh2
    float* h1    = (float*)alloc((size_t)N * 512 * 4);
    float* As1   = (float*)alloc((size_t)N * 4 * 4);
    float* Ad1   = (float*)alloc((size_t)N * 4 * 4);
    float* As2   = (float*)alloc((size_t)N * 4);
    float* Ad2   = (float*)alloc((size_t)N * 4);
    float* w_s1  = (float*)alloc(512 * 4);
    float* w_d1  = (float*)alloc(512 * 4);
    int*   startb= (int*)alloc((size_t)(N + 1) * 4);
    int*   csr   = (int*)alloc((size_t)Ep * 4);
    int*   sums  = (int*)alloc(4096);
    char* zbase = w + off;                                // zero-init group
    int*   deg    = (int*)alloc((size_t)N * 4);
    int*   cursor = (int*)alloc((size_t)N * 4);
    float* pooled = (float*)alloc((size_t)G * 128 * 4);
    int*   cnt    = (int*)alloc((size_t)G * 4);
    size_t zbytes = (size_t)((w + off) - zbase);
    float* xh2 = agg;   // agg dead after block-diag GEMM (stream-ordered)

    hipMemsetAsync(zbase, 0, zbytes, stream);

    // 1) fold attention vectors through W1, then logits straight from x
    k_wvec<<<4, 128, 0, stream>>>(W1, as1, ad1, w_s1, w_d1);
    k_attn_x<<<(N + 3) / 4, 256, 0, stream>>>(x, w_s1, w_d1, As1, Ad1, N);
    // 2) CSR by destination (self-loops appended)
    k_count<<<(Ep + 255) / 256, 256, 0, stream>>>(ei, deg, E, Ep);
    int nb = (N + 1 + 1023) / 1024;
    k_scanA<<<nb, 1024, 0, stream>>>(deg, startb, sums, N + 1, N);
    k_scanB<<<1, 64, 0, stream>>>(sums, nb);
    k_scanC<<<nb, 1024, 0, stream>>>(startb, sums, N + 1);
    k_fill<<<(Ep + 255) / 256, 256, 0, stream>>>(ei, startb, cursor, csr, E, Ep);
    // 3) layer-1 aggregation over raw x -> agg [N, 4*128]
    k_agg1x<<<N, 128, 0, stream>>>(startb, csr, As1, Ad1, x, agg, N);
    // 4) block-diagonal projection + bias + ELU: h1[:, h*128:(h+1)*128] = elu(agg_h @ W1_h^T + b1_h)
    k_gemm_big<8, true><<<dim3((N + 127) / 128, 1, 4), 256, 0, stream>>>(
        agg, W1, b1, h1, N, 128, 512, 128, 512, 128L, 16384L, 128L, 128L);
    // 5) xh2 = h1 @ W2^T   [N,128]
    k_gemm_big<4, false><<<dim3((N + 63) / 64, 1, 1), 256, 0, stream>>>(
        h1, W2, nullptr, xh2, N, 512, 512, 512, 128, 0L, 0L, 0L, 0L);
    // 6) attention logits, layer 2
    k_attn2<<<(N + 3) / 4, 256, 0, stream>>>(xh2, as2, ad2, As2, Ad2, N);
    // 7) node counts per graph
    k_cnt<<<(N + 255) / 256, 256, 0, stream>>>(bat, cnt, N);
    // 8) layer-2 aggregation (+bias+ELU) fused with mean-pool accumulation
    k_agg2<<<N, 128, 0, stream>>>(startb, csr, As2, Ad2, xh2, b2, bat, pooled, N);
    // 9) pooled mean + MLP head -> out [G]
    k_final<<<G, 128, 0, stream>>>(pooled, cnt, Wh1, bh1, Wh2, bh2, out);
}

// Round 3
// 612.136 us; speedup vs baseline: 1.5893x; 1.1828x over previous
//
#include <hip/hip_runtime.h>
#include <cstdint>
#include <cstddef>

#define NEG_SLOPE 0.2f

typedef __bf16 bf16x8 __attribute__((ext_vector_type(8)));
typedef float  f32x4  __attribute__((ext_vector_type(4)));

__device__ __forceinline__ float leaky(float x){ return x > 0.f ? x : NEG_SLOPE * x; }
__device__ __forceinline__ float elu(float x){ return x > 0.f ? x : __expf(x) - 1.f; }

__device__ __forceinline__ unsigned short bf16_rne(float f){
    unsigned u = __float_as_uint(f);
    u += 0x7fffu + ((u >> 16) & 1u);
    return (unsigned short)(u >> 16);
}
__device__ __forceinline__ float bf16_to_f32(unsigned short h){
    return __uint_as_float((unsigned)h << 16);
}

// ============ split-bf16 MFMA GEMM: C[m,n] = sum_k A[m,k]*B[n,k], N fixed = 128 ============
// a = a_hi + a_lo (bf16 each); a*b ~= ah*bh + ah*bl + al*bh  (err ~2^-16 rel)
// block 256 thr (4 waves 2x2), tile 128x128, BK=32. z-dim = independent sub-GEMMs (heads).
template<bool FUSE_BIAS_ELU>
__global__ __launch_bounds__(256, 2) void k_gemm_mfma(
    const float* __restrict__ A, const float* __restrict__ B,
    const float* __restrict__ bias, float* __restrict__ C,
    int M, int K, int lda, int ldb, int ldc,
    long aZ, long bZ, long cZ, long biasZ)
{
    constexpr int LS = 40;  // shorts per LDS row (32 + 8 pad -> 80B stride, conflict-free)
    __shared__ __align__(16) unsigned short Ah[128 * LS];
    __shared__ __align__(16) unsigned short Al[128 * LS];
    __shared__ __align__(16) unsigned short Bh[128 * LS];
    __shared__ __align__(16) unsigned short Bl[128 * LS];

    const float* Ab = A + (size_t)blockIdx.z * aZ;
    const float* Bb = B + (size_t)blockIdx.z * bZ;
    float* Cb = C + (size_t)blockIdx.z * cZ;

    const int tid = threadIdx.x;
    const int wave = tid >> 6, lane = tid & 63;
    const int wm = wave >> 1, wn = wave & 1;
    const int quad = lane >> 4, l16 = lane & 15;
    const int m0 = blockIdx.x * 128;

    f32x4 acc[4][4] = {};

    for (int k0 = 0; k0 < K; k0 += 32) {
        #pragma unroll
        for (int q = 0; q < 4; ++q) {
            int idx = tid + q * 256;            // 0..1023 float4 slots
            int row = idx >> 3, kq = idx & 7;   // row 0..127, kq 0..7 (k = kq*4)
            // ---- A ----
            float4 va = make_float4(0.f, 0.f, 0.f, 0.f);
            int rg = m0 + row;
            if (rg < M) va = *(const float4*)(Ab + (size_t)rg * lda + k0 + kq * 4);
            ushort4 hv, lv;
            hv.x = bf16_rne(va.x); lv.x = bf16_rne(va.x - bf16_to_f32(hv.x));
            hv.y = bf16_rne(va.y); lv.y = bf16_rne(va.y - bf16_to_f32(hv.y));
            hv.z = bf16_rne(va.z); lv.z = bf16_rne(va.z - bf16_to_f32(hv.z));
            hv.w = bf16_rne(va.w); lv.w = bf16_rne(va.w - bf16_to_f32(hv.w));
            *(ushort4*)&Ah[row * LS + kq * 4] = hv;
            *(ushort4*)&Al[row * LS + kq * 4] = lv;
            // ---- B ---- (N = 128 rows exactly, K multiple of 32: no guard)
            float4 vb = *(const float4*)(Bb + (size_t)row * ldb + k0 + kq * 4);
            hv.x = bf16_rne(vb.x); lv.x = bf16_rne(vb.x - bf16_to_f32(hv.x));
            hv.y = bf16_rne(vb.y); lv.y = bf16_rne(vb.y - bf16_to_f32(hv.y));
            hv.z = bf16_rne(vb.z); lv.z = bf16_rne(vb.z - bf16_to_f32(hv.z));
            hv.w = bf16_rne(vb.w); lv.w = bf16_rne(vb.w - bf16_to_f32(hv.w));
            *(ushort4*)&Bh[row * LS + kq * 4] = hv;
            *(ushort4*)&Bl[row * LS + kq * 4] = lv;
        }
        __syncthreads();

        bf16x8 ah[4], al[4], bh[4], bl[4];
        #pragma unroll
        for (int i = 0; i < 4; ++i) {
            int mr = wm * 64 + i * 16 + l16;
            ah[i] = *(const bf16x8*)&Ah[mr * LS + quad * 8];
            al[i] = *(const bf16x8*)&Al[mr * LS + quad * 8];
            int nr = wn * 64 + i * 16 + l16;
            bh[i] = *(const bf16x8*)&Bh[nr * LS + quad * 8];
            bl[i] = *(const bf16x8*)&Bl[nr * LS + quad * 8];
        }
        #pragma unroll
        for (int i = 0; i < 4; ++i)
            #pragma unroll
            for (int j = 0; j < 4; ++j) {
                acc[i][j] = __builtin_amdgcn_mfma_f32_16x16x32_bf16(ah[i], bh[j], acc[i][j], 0, 0, 0);
                acc[i][j] = __builtin_amdgcn_mfma_f32_16x16x32_bf16(ah[i], bl[j], acc[i][j], 0, 0, 0);
                acc[i][j] = __builtin_amdgcn_mfma_f32_16x16x32_bf16(al[i], bh[j], acc[i][j], 0, 0, 0);
            }
        __syncthreads();
    }

    #pragma unroll
    for (int j = 0; j < 4; ++j) {
        int n = wn * 64 + j * 16 + l16;
        float bb = 0.f;
        if (FUSE_BIAS_ELU) bb = bias[blockIdx.z * biasZ + n];
        #pragma unroll
        for (int i = 0; i < 4; ++i)
            #pragma unroll
            for (int r = 0; r < 4; ++r) {
                int m = m0 + wm * 64 + i * 16 + quad * 4 + r;
                if (m < M) {
                    float v = acc[i][j][r];
                    if (FUSE_BIAS_ELU) v = elu(v + bb);
                    Cb[(size_t)m * ldc + n] = v;
                }
            }
    }
}

// ============ fold attention vectors: w_s[h,k] = sum_c att_src[h,c] * W1[h*128+c, k] ============
__global__ __launch_bounds__(128) void k_wvec(const float* __restrict__ W1,
                                              const float* __restrict__ as1,
                                              const float* __restrict__ ad1,
                                              float* __restrict__ w_s,
                                              float* __restrict__ w_d)
{
    int h = blockIdx.x, k = threadIdx.x;
    float s = 0.f, d = 0.f;
    for (int c = 0; c < 128; ++c) {
        float w = W1[((size_t)(h * 128 + c)) * 128 + k];
        s += as1[h * 128 + c] * w;
        d += ad1[h * 128 + c] * w;
    }
    w_s[h * 128 + k] = s;
    w_d[h * 128 + k] = d;
}

// ============ layer-1 attention logits from raw x ============
__global__ __launch_bounds__(256) void k_attn_x(const float* __restrict__ x,
                                                const float* __restrict__ w_s,
                                                const float* __restrict__ w_d,
                                                float* __restrict__ a_s,
                                                float* __restrict__ a_d, int N)
{
    int n = blockIdx.x * 4 + (threadIdx.x >> 6);
    if (n >= N) return;
    int lane = threadIdx.x & 63;
    float2 xv = *(const float2*)(x + (size_t)n * 128 + lane * 2);
    float ps[4], pd[4];
    #pragma unroll
    for (int h = 0; h < 4; ++h) {
        float2 sv = *(const float2*)(w_s + h * 128 + lane * 2);
        float2 dv = *(const float2*)(w_d + h * 128 + lane * 2);
        ps[h] = xv.x * sv.x + xv.y * sv.y;
        pd[h] = xv.x * dv.x + xv.y * dv.y;
    }
    #pragma unroll
    for (int h = 0; h < 4; ++h)
        for (int off = 32; off; off >>= 1) {
            ps[h] += __shfl_xor(ps[h], off);
            pd[h] += __shfl_xor(pd[h], off);
        }
    if (lane == 0) {
        *(float4*)(a_s + (size_t)n * 4) = make_float4(ps[0], ps[1], ps[2], ps[3]);
        *(float4*)(a_d + (size_t)n * 4) = make_float4(pd[0], pd[1], pd[2], pd[3]);
    }
}

// ============ layer-2 attention logits (H=1, C=128) ============
__global__ __launch_bounds__(256) void k_attn2(const float* __restrict__ xh,
                                               const float* __restrict__ as2,
                                               const float* __restrict__ ad2,
                                               float* __restrict__ a_s,
                                               float* __restrict__ a_d, int N)
{
    int n = blockIdx.x * 4 + (threadIdx.x >> 6);
    if (n >= N) return;
    int lane = threadIdx.x & 63;
    float2 xv = *(const float2*)(xh + (size_t)n * 128 + lane * 2);
    float2 sv = *(const float2*)(as2 + lane * 2);
    float2 dv = *(const float2*)(ad2 + lane * 2);
    float ps = xv.x * sv.x + xv.y * sv.y;
    float pd = xv.x * dv.x + xv.y * dv.y;
    for (int off = 32; off; off >>= 1) { ps += __shfl_xor(ps, off); pd += __shfl_xor(pd, off); }
    if (lane == 0) { a_s[n] = ps; a_d[n] = pd; }
}

// ============ CSR construction ============
__global__ void k_count(const int* __restrict__ ei, int* __restrict__ deg, int E, int Ep)
{
    int e = blockIdx.x * blockDim.x + threadIdx.x;
    if (e >= Ep) return;
    int dst = (e < E) ? ei[E + e] : (e - E);
    atomicAdd(&deg[dst], 1);
}

__global__ __launch_bounds__(1024) void k_scanA(const int* __restrict__ deg,
                                                int* __restrict__ start,
                                                int* __restrict__ sums, int Ntot, int N)
{
    __shared__ int sm[1024];
    int tid = threadIdx.x;
    int i = blockIdx.x * 1024 + tid;
    int v = (i < N) ? deg[i] : 0;
    sm[tid] = v; __syncthreads();
    for (int off = 1; off < 1024; off <<= 1) {
        int t = (tid >= off) ? sm[tid - off] : 0;
        __syncthreads();
        sm[tid] += t;
        __syncthreads();
    }
    if (i < Ntot) start[i] = sm[tid] - v;
    if (tid == 1023) sums[blockIdx.x] = sm[1023];
}

__global__ void k_scanB(int* sums, int nb)
{
    int l = threadIdx.x;
    int v = (l < nb) ? sums[l] : 0;
    int orig = v;
    for (int off = 1; off < 64; off <<= 1) { int t = __shfl_up(v, off); if (l >= off) v += t; }
    if (l < nb) sums[l] = v - orig;
}

__global__ __launch_bounds__(1024) void k_scanC(int* __restrict__ start,
                                                const int* __restrict__ sums, int Ntot)
{
    int i = blockIdx.x * 1024 + threadIdx.x;
    if (i < Ntot) start[i] += sums[blockIdx.x];
}

__global__ void k_fill(const int* __restrict__ ei, const int* __restrict__ start,
                       int* __restrict__ cursor, int* __restrict__ csr_src, int E, int Ep)
{
    int e = blockIdx.x * blockDim.x + threadIdx.x;
    if (e >= Ep) return;
    int src, dst;
    if (e < E) { src = ei[e]; dst = ei[E + e]; } else { src = dst = e - E; }
    int pos = atomicAdd(&cursor[dst], 1);
    csr_src[start[dst] + pos] = src;
}

// ============ layer-1 aggregation over RAW x (128-dim), 4 heads ============
#define CAPA 256
__global__ __launch_bounds__(128) void k_agg1x(const int* __restrict__ start,
                                               const int* __restrict__ csr_src,
                                               const float* __restrict__ a_s,
                                               const float* __restrict__ a_d,
                                               const float* __restrict__ x,
                                               float* __restrict__ agg, int N)
{
    int d = blockIdx.x, tid = threadIdx.x;
    __shared__ float s_al[CAPA * 4];
    __shared__ int   s_src[CAPA];
    __shared__ float red[4 * 128];
    __shared__ float s_inv[4];

    int beg = start[d], end = start[d + 1];
    int deg = end - beg;
    float4 ad4 = *(const float4*)(a_d + (size_t)d * 4);

    float ps0 = 0, ps1 = 0, ps2 = 0, ps3 = 0;
    for (int i = tid; i < deg; i += 128) {
        int s = csr_src[beg + i];
        float4 as4 = *(const float4*)(a_s + (size_t)s * 4);
        float e0 = __expf(leaky(as4.x + ad4.x));
        float e1 = __expf(leaky(as4.y + ad4.y));
        float e2 = __expf(leaky(as4.z + ad4.z));
        float e3 = __expf(leaky(as4.w + ad4.w));
        ps0 += e0; ps1 += e1; ps2 += e2; ps3 += e3;
        if (i < CAPA) { s_src[i] = s; *(float4*)&s_al[i*4] = make_float4(e0, e1, e2, e3); }
    }
    red[tid] = ps0; red[128+tid] = ps1; red[256+tid] = ps2; red[384+tid] = ps3;
    __syncthreads();
    for (int st = 64; st > 0; st >>= 1) {
        if (tid < st) {
            red[tid]     += red[tid+st];
            red[128+tid] += red[128+tid+st];
            red[256+tid] += red[256+tid+st];
            red[384+tid] += red[384+tid+st];
        }
        __syncthreads();
    }
    if (tid < 4) s_inv[tid] = 1.f / (red[tid*128] + 1e-16f);
    __syncthreads();
    int ncap4 = (deg < CAPA ? deg : CAPA) * 4;
    for (int j = tid; j < ncap4; j += 128) s_al[j] *= s_inv[j & 3];
    __syncthreads();

    float inv0 = s_inv[0], inv1 = s_inv[1], inv2 = s_inv[2], inv3 = s_inv[3];
    int c = tid;
    float acc0 = 0.f, acc1 = 0.f, acc2 = 0.f, acc3 = 0.f;
    for (int i = 0; i < deg; ++i) {
        float4 al; int s;
        if (i < CAPA) { al = *(const float4*)&s_al[i*4]; s = s_src[i]; }
        else {
            s = csr_src[beg + i];
            float4 as4 = *(const float4*)(a_s + (size_t)s * 4);
            al.x = __expf(leaky(as4.x + ad4.x)) * inv0;
            al.y = __expf(leaky(as4.y + ad4.y)) * inv1;
            al.z = __expf(leaky(as4.z + ad4.z)) * inv2;
            al.w = __expf(leaky(as4.w + ad4.w)) * inv3;
        }
        float xv = x[(size_t)s * 128 + c];
        acc0 += al.x * xv; acc1 += al.y * xv; acc2 += al.z * xv; acc3 += al.w * xv;
    }
    float* o = agg + (size_t)d * 512 + c;
    o[0]   = acc0;
    o[128] = acc1;
    o[256] = acc2;
    o[384] = acc3;
}

// ============ layer-2 aggregation + bias + ELU -> h2[N,128] (no atomics) ============
#define CAP2 256
__global__ __launch_bounds__(128) void k_agg2(const int* __restrict__ start,
                                              const int* __restrict__ csr_src,
                                              const float* __restrict__ a_s,
                                              const float* __restrict__ a_d,
                                              const float* __restrict__ xh2,
                                              const float* __restrict__ b2,
                                              float* __restrict__ h2, int N)
{
    int d = blockIdx.x, tid = threadIdx.x;
    __shared__ float s_alpha[CAP2];
    __shared__ int   s_src[CAP2];
    __shared__ float red[128];
    __shared__ float s_invs;

    int beg = start[d], end = start[d + 1];
    int deg = end - beg;
    float ad = a_d[d];
    float ps = 0.f;
    for (int i = tid; i < deg; i += 128) {
        int s = csr_src[beg + i];
        float e = __expf(leaky(a_s[s] + ad));
        ps += e;
        if (i < CAP2) { s_src[i] = s; s_alpha[i] = e; }
    }
    red[tid] = ps; __syncthreads();
    for (int st = 64; st > 0; st >>= 1) { if (tid < st) red[tid] += red[tid+st]; __syncthreads(); }
    if (tid == 0) s_invs = 1.f / (red[0] + 1e-16f);
    __syncthreads();
    float inv = s_invs;
    float acc = 0.f;
    for (int i = 0; i < deg; ++i) {
        float al; int s;
        if (i < CAP2) { al = s_alpha[i] * inv; s = s_src[i]; }
        else { s = csr_src[beg + i]; al = __expf(leaky(a_s[s] + ad)) * inv; }
        acc += al * xh2[(size_t)s * 128 + tid];
    }
    h2[(size_t)d * 128 + tid] = elu(acc + b2[tid]);
}

// ============ graph boundaries from SORTED batch (no atomics) ============
// gstart[g] = first node index with batch >= g; gstart[G] = N
__global__ void k_gbound(const int* __restrict__ batch, int* __restrict__ gstart, int N, int G)
{
    int n = blockIdx.x * blockDim.x + threadIdx.x;
    if (n >= N) return;
    int b = batch[n];
    int prev = (n == 0) ? -1 : batch[n - 1];
    for (int g = prev + 1; g <= b; ++g) gstart[g] = n;
    if (n == N - 1)
        for (int g = b + 1; g <= G; ++g) gstart[g] = N;
}

// ============ fused mean-pool + MLP head: out[g] ============
__global__ __launch_bounds__(128) void k_poolhead(const float* __restrict__ h2,
                                                  const int* __restrict__ gstart,
                                                  const float* __restrict__ Wh1,
                                                  const float* __restrict__ bh1,
                                                  const float* __restrict__ Wh2,
                                                  const float* __restrict__ bh2,
                                                  float* __restrict__ out)
{
    int g = blockIdx.x, c = threadIdx.x;
    __shared__ float p[128];
    __shared__ float red[128];
    int s = gstart[g], e = gstart[g + 1];
    float acc = 0.f;
    for (int n = s; n < e; ++n) acc += h2[(size_t)n * 128 + c];
    float cf = (float)(e - s); cf = cf > 1.f ? cf : 1.f;
    p[c] = acc / cf;
    __syncthreads();
    float z = bh1[c];
    for (int k = 0; k < 128; ++k) z += p[k] * Wh1[c * 128 + k];
    z = z > 0.f ? z : 0.f;
    red[c] = z * Wh2[c];
    __syncthreads();
    for (int st = 64; st > 0; st >>= 1) { if (c < st) red[c] += red[c + st]; __syncthreads(); }
    if (c == 0) out[g] = red[0] + bh2[0];
}

// ============ launch ============
extern "C" void kernel_launch(void* const* d_in, const int* in_sizes, int n_in,
                              void* d_out, int out_size, void* d_ws, size_t ws_size,
                              hipStream_t stream)
{
    const float* x   = (const float*)d_in[0];
    const int*   ei  = (const int*)d_in[1];
    const int*   bat = (const int*)d_in[2];
    const float* W1  = (const float*)d_in[3];
    const float* as1 = (const float*)d_in[4];
    const float* ad1 = (const float*)d_in[5];
    const float* b1  = (const float*)d_in[6];
    const float* W2  = (const float*)d_in[7];
    const float* as2 = (const float*)d_in[8];
    const float* ad2 = (const float*)d_in[9];
    const float* b2  = (const float*)d_in[10];
    const float* Wh1 = (const float*)d_in[11];
    const float* bh1 = (const float*)d_in[12];
    const float* Wh2 = (const float*)d_in[13];
    const float* bh2 = (const float*)d_in[14];
    float* out = (float*)d_out;

    const int N  = in_sizes[0] / 128;
    const int E  = in_sizes[1] / 2;
    const int Ep = E + N;
    const int G  = 128;

    char* w = (char*)d_ws;
    size_t off = 0;
    auto alloc = [&](size_t bytes) -> char* {
        char* p = w + off; off += (bytes + 511) & ~(size_t)511; return p;
    };
    float* agg   = (float*)alloc((size_t)N * 512 * 4);   // layer-1 aggregated x; reused as xh2
    float* h1    = (float*)alloc((size_t)N * 512 * 4);   // reused as h2
    float* As1   = (float*)alloc((size_t)N * 4 * 4);
    float* Ad1   = (float*)alloc((size_t)N * 4 * 4);
    float* As2   = (float*)alloc((size_t)N * 4);
    float* Ad2   = (float*)alloc((size_t)N * 4);
    float* w_s1  = (float*)alloc(512 * 4);
    float* w_d1  = (float*)alloc(512 * 4);
    int*   startb= (int*)alloc((size_t)(N + 1) * 4);
    int*   csr   = (int*)alloc((size_t)Ep * 4);
    int*   sums  = (int*)alloc(4096);
    int*   gstart= (int*)alloc((size_t)(G + 1) * 4);
    char* zbase = w + off;                                // zero-init group
    int*   deg    = (int*)alloc((size_t)N * 4);
    int*   cursor = (int*)alloc((size_t)N * 4);
    size_t zbytes = (size_t)((w + off) - zbase);
    float* xh2 = agg;    // agg dead after GEMM1 (stream-ordered)
    float* h2  = h1;     // h1 dead after GEMM2

    hipMemsetAsync(zbase, 0, zbytes, stream);

    // 1) attention logits straight from x (fold att vectors through W1)
    k_wvec<<<4, 128, 0, stream>>>(W1, as1, ad1, w_s1, w_d1);
    k_attn_x<<<(N + 3) / 4, 256, 0, stream>>>(x, w_s1, w_d1, As1, Ad1, N);
    // 2) CSR by destination (self-loops appended)
    k_count<<<(Ep + 255) / 256, 256, 0, stream>>>(ei, deg, E, Ep);
    int nb = (N + 1 + 1023) / 1024;
    k_scanA<<<nb, 1024, 0, stream>>>(deg, startb, sums, N + 1, N);
    k_scanB<<<1, 64, 0, stream>>>(sums, nb);
    k_scanC<<<nb, 1024, 0, stream>>>(startb, sums, N + 1);
    k_fill<<<(Ep + 255) / 256, 256, 0, stream>>>(ei, startb, cursor, csr, E, Ep);
    // 3) graph boundaries (batch sorted)
    k_gbound<<<(N + 255) / 256, 256, 0, stream>>>(bat, gstart, N, G);
    // 4) layer-1 aggregation over raw x -> agg [N, 4*128]
    k_agg1x<<<N, 128, 0, stream>>>(startb, csr, As1, Ad1, x, agg, N);
    // 5) block-diag projection + bias + ELU (split-bf16 MFMA): h1_h = elu(agg_h @ W1_h^T + b1_h)
    k_gemm_mfma<true><<<dim3((N + 127) / 128, 1, 4), 256, 0, stream>>>(
        agg, W1, b1, h1, N, 128, 512, 128, 512, 128L, 16384L, 128L, 128L);
    // 6) xh2 = h1 @ W2^T  [N,128]  (split-bf16 MFMA)
    k_gemm_mfma<false><<<dim3((N + 127) / 128, 1, 1), 256, 0, stream>>>(
        h1, W2, nullptr, xh2, N, 512, 512, 512, 128, 0L, 0L, 0L, 0L);
    // 7) layer-2 attention logits
    k_attn2<<<(N + 3) / 4, 256, 0, stream>>>(xh2, as2, ad2, As2, Ad2, N);
    // 8) layer-2 aggregation + bias + ELU -> h2 [N,128]
    k_agg2<<<N, 128, 0, stream>>>(startb, csr, As2, Ad2, xh2, b2, h2, N);
    // 9) fused mean-pool + MLP head
    k_poolhead<<<G, 128, 0, stream>>>(h2, gstart, Wh1, bh1, Wh2, bh2, out);
}

// Round 4
// 537.544 us; speedup vs baseline: 1.8099x; 1.1388x over previous
//
#include <hip/hip_runtime.h>
#include <cstdint>
#include <cstddef>

#define NEG_SLOPE 0.2f

typedef __bf16 bf16x8 __attribute__((ext_vector_type(8)));
typedef float  f32x4  __attribute__((ext_vector_type(4)));

__device__ __forceinline__ float leaky(float x){ return x > 0.f ? x : NEG_SLOPE * x; }
__device__ __forceinline__ float elu(float x){ return x > 0.f ? x : __expf(x) - 1.f; }

__device__ __forceinline__ unsigned short bf16_rne(float f){
    unsigned u = __float_as_uint(f);
    u += 0x7fffu + ((u >> 16) & 1u);
    return (unsigned short)(u >> 16);
}
__device__ __forceinline__ float bf16_to_f32(unsigned short h){
    return __uint_as_float((unsigned)h << 16);
}

// ============ split-bf16 MFMA GEMM: C[m,n] = sum_k A[m,k]*B[n,k], N fixed = 128 ============
// a = a_hi + a_lo (bf16 each); a*b ~= ah*bh + ah*bl + al*bh  (err ~2^-16 rel)
// block 256 thr (4 waves 2x2), tile 128x128, BK=32. z-dim = independent sub-GEMMs (heads).
template<bool FUSE_BIAS_ELU>
__global__ __launch_bounds__(256, 2) void k_gemm_mfma(
    const float* __restrict__ A, const float* __restrict__ B,
    const float* __restrict__ bias, float* __restrict__ C,
    int M, int K, int lda, int ldb, int ldc,
    long aZ, long bZ, long cZ, long biasZ)
{
    constexpr int LS = 40;  // shorts per LDS row (32 + 8 pad -> 80B stride, conflict-free)
    __shared__ __align__(16) unsigned short Ah[128 * LS];
    __shared__ __align__(16) unsigned short Al[128 * LS];
    __shared__ __align__(16) unsigned short Bh[128 * LS];
    __shared__ __align__(16) unsigned short Bl[128 * LS];

    const float* Ab = A + (size_t)blockIdx.z * aZ;
    const float* Bb = B + (size_t)blockIdx.z * bZ;
    float* Cb = C + (size_t)blockIdx.z * cZ;

    const int tid = threadIdx.x;
    const int wave = tid >> 6, lane = tid & 63;
    const int wm = wave >> 1, wn = wave & 1;
    const int quad = lane >> 4, l16 = lane & 15;
    const int m0 = blockIdx.x * 128;

    f32x4 acc[4][4] = {};

    for (int k0 = 0; k0 < K; k0 += 32) {
        #pragma unroll
        for (int q = 0; q < 4; ++q) {
            int idx = tid + q * 256;            // 0..1023 float4 slots
            int row = idx >> 3, kq = idx & 7;   // row 0..127, kq 0..7 (k = kq*4)
            // ---- A ----
            float4 va = make_float4(0.f, 0.f, 0.f, 0.f);
            int rg = m0 + row;
            if (rg < M) va = *(const float4*)(Ab + (size_t)rg * lda + k0 + kq * 4);
            ushort4 hv, lv;
            hv.x = bf16_rne(va.x); lv.x = bf16_rne(va.x - bf16_to_f32(hv.x));
            hv.y = bf16_rne(va.y); lv.y = bf16_rne(va.y - bf16_to_f32(hv.y));
            hv.z = bf16_rne(va.z); lv.z = bf16_rne(va.z - bf16_to_f32(hv.z));
            hv.w = bf16_rne(va.w); lv.w = bf16_rne(va.w - bf16_to_f32(hv.w));
            *(ushort4*)&Ah[row * LS + kq * 4] = hv;
            *(ushort4*)&Al[row * LS + kq * 4] = lv;
            // ---- B ---- (N = 128 rows exactly, K multiple of 32: no guard)
            float4 vb = *(const float4*)(Bb + (size_t)row * ldb + k0 + kq * 4);
            hv.x = bf16_rne(vb.x); lv.x = bf16_rne(vb.x - bf16_to_f32(hv.x));
            hv.y = bf16_rne(vb.y); lv.y = bf16_rne(vb.y - bf16_to_f32(hv.y));
            hv.z = bf16_rne(vb.z); lv.z = bf16_rne(vb.z - bf16_to_f32(hv.z));
            hv.w = bf16_rne(vb.w); lv.w = bf16_rne(vb.w - bf16_to_f32(hv.w));
            *(ushort4*)&Bh[row * LS + kq * 4] = hv;
            *(ushort4*)&Bl[row * LS + kq * 4] = lv;
        }
        __syncthreads();

        bf16x8 ah[4], al[4], bh[4], bl[4];
        #pragma unroll
        for (int i = 0; i < 4; ++i) {
            int mr = wm * 64 + i * 16 + l16;
            ah[i] = *(const bf16x8*)&Ah[mr * LS + quad * 8];
            al[i] = *(const bf16x8*)&Al[mr * LS + quad * 8];
            int nr = wn * 64 + i * 16 + l16;
            bh[i] = *(const bf16x8*)&Bh[nr * LS + quad * 8];
            bl[i] = *(const bf16x8*)&Bl[nr * LS + quad * 8];
        }
        #pragma unroll
        for (int i = 0; i < 4; ++i)
            #pragma unroll
            for (int j = 0; j < 4; ++j) {
                acc[i][j] = __builtin_amdgcn_mfma_f32_16x16x32_bf16(ah[i], bh[j], acc[i][j], 0, 0, 0);
                acc[i][j] = __builtin_amdgcn_mfma_f32_16x16x32_bf16(ah[i], bl[j], acc[i][j], 0, 0, 0);
                acc[i][j] = __builtin_amdgcn_mfma_f32_16x16x32_bf16(al[i], bh[j], acc[i][j], 0, 0, 0);
            }
        __syncthreads();
    }

    #pragma unroll
    for (int j = 0; j < 4; ++j) {
        int n = wn * 64 + j * 16 + l16;
        float bb = 0.f;
        if (FUSE_BIAS_ELU) bb = bias[blockIdx.z * biasZ + n];
        #pragma unroll
        for (int i = 0; i < 4; ++i)
            #pragma unroll
            for (int r = 0; r < 4; ++r) {
                int m = m0 + wm * 64 + i * 16 + quad * 4 + r;
                if (m < M) {
                    float v = acc[i][j][r];
                    if (FUSE_BIAS_ELU) v = elu(v + bb);
                    Cb[(size_t)m * ldc + n] = v;
                }
            }
    }
}

// ============ fold attention vectors: w_s[h,k] = sum_c att_src[h,c] * W1[h*128+c, k] ============
__global__ __launch_bounds__(128) void k_wvec(const float* __restrict__ W1,
                                              const float* __restrict__ as1,
                                              const float* __restrict__ ad1,
                                              float* __restrict__ w_s,
                                              float* __restrict__ w_d)
{
    int h = blockIdx.x, k = threadIdx.x;
    float s = 0.f, d = 0.f;
    for (int c = 0; c < 128; ++c) {
        float w = W1[((size_t)(h * 128 + c)) * 128 + k];
        s += as1[h * 128 + c] * w;
        d += ad1[h * 128 + c] * w;
    }
    w_s[h * 128 + k] = s;
    w_d[h * 128 + k] = d;
}

// ============ layer-1 attention logits from raw x ============
__global__ __launch_bounds__(256) void k_attn_x(const float* __restrict__ x,
                                                const float* __restrict__ w_s,
                                                const float* __restrict__ w_d,
                                                float* __restrict__ a_s,
                                                float* __restrict__ a_d, int N)
{
    int n = blockIdx.x * 4 + (threadIdx.x >> 6);
    if (n >= N) return;
    int lane = threadIdx.x & 63;
    float2 xv = *(const float2*)(x + (size_t)n * 128 + lane * 2);
    float ps[4], pd[4];
    #pragma unroll
    for (int h = 0; h < 4; ++h) {
        float2 sv = *(const float2*)(w_s + h * 128 + lane * 2);
        float2 dv = *(const float2*)(w_d + h * 128 + lane * 2);
        ps[h] = xv.x * sv.x + xv.y * sv.y;
        pd[h] = xv.x * dv.x + xv.y * dv.y;
    }
    #pragma unroll
    for (int h = 0; h < 4; ++h)
        for (int off = 32; off; off >>= 1) {
            ps[h] += __shfl_xor(ps[h], off);
            pd[h] += __shfl_xor(pd[h], off);
        }
    if (lane == 0) {
        *(float4*)(a_s + (size_t)n * 4) = make_float4(ps[0], ps[1], ps[2], ps[3]);
        *(float4*)(a_d + (size_t)n * 4) = make_float4(pd[0], pd[1], pd[2], pd[3]);
    }
}

// ============ layer-2 attention logits (H=1, C=128) ============
__global__ __launch_bounds__(256) void k_attn2(const float* __restrict__ xh,
                                               const float* __restrict__ as2,
                                               const float* __restrict__ ad2,
                                               float* __restrict__ a_s,
                                               float* __restrict__ a_d, int N)
{
    int n = blockIdx.x * 4 + (threadIdx.x >> 6);
    if (n >= N) return;
    int lane = threadIdx.x & 63;
    float2 xv = *(const float2*)(xh + (size_t)n * 128 + lane * 2);
    float2 sv = *(const float2*)(as2 + lane * 2);
    float2 dv = *(const float2*)(ad2 + lane * 2);
    float ps = xv.x * sv.x + xv.y * sv.y;
    float pd = xv.x * dv.x + xv.y * dv.y;
    for (int off = 32; off; off >>= 1) { ps += __shfl_xor(ps, off); pd += __shfl_xor(pd, off); }
    if (lane == 0) { a_s[n] = ps; a_d[n] = pd; }
}

// ============ CSR construction ============
__global__ void k_count(const int* __restrict__ ei, int* __restrict__ deg, int E, int Ep)
{
    int e = blockIdx.x * blockDim.x + threadIdx.x;
    if (e >= Ep) return;
    int dst = (e < E) ? ei[E + e] : (e - E);
    atomicAdd(&deg[dst], 1);
}

__global__ __launch_bounds__(1024) void k_scanA(const int* __restrict__ deg,
                                                int* __restrict__ start,
                                                int* __restrict__ sums, int Ntot, int N)
{
    __shared__ int sm[1024];
    int tid = threadIdx.x;
    int i = blockIdx.x * 1024 + tid;
    int v = (i < N) ? deg[i] : 0;
    sm[tid] = v; __syncthreads();
    for (int off = 1; off < 1024; off <<= 1) {
        int t = (tid >= off) ? sm[tid - off] : 0;
        __syncthreads();
        sm[tid] += t;
        __syncthreads();
    }
    if (i < Ntot) start[i] = sm[tid] - v;
    if (tid == 1023) sums[blockIdx.x] = sm[1023];
}

__global__ void k_scanB(int* sums, int nb)
{
    int l = threadIdx.x;
    int v = (l < nb) ? sums[l] : 0;
    int orig = v;
    for (int off = 1; off < 64; off <<= 1) { int t = __shfl_up(v, off); if (l >= off) v += t; }
    if (l < nb) sums[l] = v - orig;
}

__global__ __launch_bounds__(1024) void k_scanC(int* __restrict__ start,
                                                const int* __restrict__ sums, int Ntot)
{
    int i = blockIdx.x * 1024 + threadIdx.x;
    if (i < Ntot) start[i] += sums[blockIdx.x];
}

__global__ void k_fill(const int* __restrict__ ei, const int* __restrict__ start,
                       int* __restrict__ cursor, int* __restrict__ csr_src, int E, int Ep)
{
    int e = blockIdx.x * blockDim.x + threadIdx.x;
    if (e >= Ep) return;
    int src, dst;
    if (e < E) { src = ei[e]; dst = ei[E + e]; } else { src = dst = e - E; }
    int pos = atomicAdd(&cursor[dst], 1);
    csr_src[start[dst] + pos] = src;
}

// ============ layer-1 aggregation over RAW x (128-dim), 4 heads ============
#define CAPA 256
__global__ __launch_bounds__(128) void k_agg1x(const int* __restrict__ start,
                                               const int* __restrict__ csr_src,
                                               const float* __restrict__ a_s,
                                               const float* __restrict__ a_d,
                                               const float* __restrict__ x,
                                               float* __restrict__ agg, int N)
{
    int d = blockIdx.x, tid = threadIdx.x;
    __shared__ float s_al[CAPA * 4];
    __shared__ int   s_src[CAPA];
    __shared__ float red[4 * 128];
    __shared__ float s_inv[4];

    int beg = start[d], end = start[d + 1];
    int deg = end - beg;
    float4 ad4 = *(const float4*)(a_d + (size_t)d * 4);

    float ps0 = 0, ps1 = 0, ps2 = 0, ps3 = 0;
    for (int i = tid; i < deg; i += 128) {
        int s = csr_src[beg + i];
        float4 as4 = *(const float4*)(a_s + (size_t)s * 4);
        float e0 = __expf(leaky(as4.x + ad4.x));
        float e1 = __expf(leaky(as4.y + ad4.y));
        float e2 = __expf(leaky(as4.z + ad4.z));
        float e3 = __expf(leaky(as4.w + ad4.w));
        ps0 += e0; ps1 += e1; ps2 += e2; ps3 += e3;
        if (i < CAPA) { s_src[i] = s; *(float4*)&s_al[i*4] = make_float4(e0, e1, e2, e3); }
    }
    red[tid] = ps0; red[128+tid] = ps1; red[256+tid] = ps2; red[384+tid] = ps3;
    __syncthreads();
    for (int st = 64; st > 0; st >>= 1) {
        if (tid < st) {
            red[tid]     += red[tid+st];
            red[128+tid] += red[128+tid+st];
            red[256+tid] += red[256+tid+st];
            red[384+tid] += red[384+tid+st];
        }
        __syncthreads();
    }
    if (tid < 4) s_inv[tid] = 1.f / (red[tid*128] + 1e-16f);
    __syncthreads();
    int ncap4 = (deg < CAPA ? deg : CAPA) * 4;
    for (int j = tid; j < ncap4; j += 128) s_al[j] *= s_inv[j & 3];
    __syncthreads();

    float inv0 = s_inv[0], inv1 = s_inv[1], inv2 = s_inv[2], inv3 = s_inv[3];
    int c = tid;
    float acc0 = 0.f, acc1 = 0.f, acc2 = 0.f, acc3 = 0.f;
    for (int i = 0; i < deg; ++i) {
        float4 al; int s;
        if (i < CAPA) { al = *(const float4*)&s_al[i*4]; s = s_src[i]; }
        else {
            s = csr_src[beg + i];
            float4 as4 = *(const float4*)(a_s + (size_t)s * 4);
            al.x = __expf(leaky(as4.x + ad4.x)) * inv0;
            al.y = __expf(leaky(as4.y + ad4.y)) * inv1;
            al.z = __expf(leaky(as4.z + ad4.z)) * inv2;
            al.w = __expf(leaky(as4.w + ad4.w)) * inv3;
        }
        float xv = x[(size_t)s * 128 + c];
        acc0 += al.x * xv; acc1 += al.y * xv; acc2 += al.z * xv; acc3 += al.w * xv;
    }
    float* o = agg + (size_t)d * 512 + c;
    o[0]   = acc0;
    o[128] = acc1;
    o[256] = acc2;
    o[384] = acc3;
}

// ============ layer-2 aggregation + bias + ELU -> h2[N,128] (no atomics) ============
#define CAP2 256
__global__ __launch_bounds__(128) void k_agg2(const int* __restrict__ start,
                                              const int* __restrict__ csr_src,
                                              const float* __restrict__ a_s,
                                              const float* __restrict__ a_d,
                                              const float* __restrict__ xh2,
                                              const float* __restrict__ b2,
                                              float* __restrict__ h2, int N)
{
    int d = blockIdx.x, tid = threadIdx.x;
    __shared__ float s_alpha[CAP2];
    __shared__ int   s_src[CAP2];
    __shared__ float red[128];
    __shared__ float s_invs;

    int beg = start[d], end = start[d + 1];
    int deg = end - beg;
    float ad = a_d[d];
    float ps = 0.f;
    for (int i = tid; i < deg; i += 128) {
        int s = csr_src[beg + i];
        float e = __expf(leaky(a_s[s] + ad));
        ps += e;
        if (i < CAP2) { s_src[i] = s; s_alpha[i] = e; }
    }
    red[tid] = ps; __syncthreads();
    for (int st = 64; st > 0; st >>= 1) { if (tid < st) red[tid] += red[tid+st]; __syncthreads(); }
    if (tid == 0) s_invs = 1.f / (red[0] + 1e-16f);
    __syncthreads();
    float inv = s_invs;
    float acc = 0.f;
    for (int i = 0; i < deg; ++i) {
        float al; int s;
        if (i < CAP2) { al = s_alpha[i] * inv; s = s_src[i]; }
        else { s = csr_src[beg + i]; al = __expf(leaky(a_s[s] + ad)) * inv; }
        acc += al * xh2[(size_t)s * 128 + tid];
    }
    h2[(size_t)d * 128 + tid] = elu(acc + b2[tid]);
}

// ============ graph boundaries from SORTED batch (no atomics) ============
__global__ void k_gbound(const int* __restrict__ batch, int* __restrict__ gstart, int N, int G)
{
    int n = blockIdx.x * blockDim.x + threadIdx.x;
    if (n >= N) return;
    int b = batch[n];
    int prev = (n == 0) ? -1 : batch[n - 1];
    for (int g = prev + 1; g <= b; ++g) gstart[g] = n;
    if (n == N - 1)
        for (int g = b + 1; g <= G; ++g) gstart[g] = N;
}

// ============ pooling stage A: chunked partial sums (full occupancy, few atomics) ============
#define PCH 64
__global__ __launch_bounds__(128) void k_poolA(const float* __restrict__ h2,
                                               const int* __restrict__ batch,
                                               float* __restrict__ pooled, int N)
{
    int c = threadIdx.x;
    int n0 = blockIdx.x * PCH;
    int n1 = n0 + PCH < N ? n0 + PCH : N;
    if (n0 >= N) return;
    int g = batch[n0];
    float acc = 0.f;
    for (int n = n0; n < n1; ++n) {
        int bg = batch[n];
        if (bg != g) { atomicAdd(&pooled[(size_t)g * 128 + c], acc); acc = 0.f; g = bg; }
        acc += h2[(size_t)n * 128 + c];
    }
    atomicAdd(&pooled[(size_t)g * 128 + c], acc);
}

// ============ head: mean + relu(pooled@Wh1^T+bh1) @ Wh2^T + bh2 ============
__global__ __launch_bounds__(128) void k_head(const float* __restrict__ pooled,
                                              const int* __restrict__ gstart,
                                              const float* __restrict__ Wh1,
                                              const float* __restrict__ bh1,
                                              const float* __restrict__ Wh2,
                                              const float* __restrict__ bh2,
                                              float* __restrict__ out)
{
    int g = blockIdx.x, c = threadIdx.x;
    __shared__ float p[128];
    __shared__ float red[128];
    float cf = (float)(gstart[g + 1] - gstart[g]); cf = cf > 1.f ? cf : 1.f;
    p[c] = pooled[(size_t)g * 128 + c] / cf;
    __syncthreads();
    float z = bh1[c];
    for (int k = 0; k < 128; ++k) z += p[k] * Wh1[c * 128 + k];
    z = z > 0.f ? z : 0.f;
    red[c] = z * Wh2[c];
    __syncthreads();
    for (int st = 64; st > 0; st >>= 1) { if (c < st) red[c] += red[c + st]; __syncthreads(); }
    if (c == 0) out[g] = red[0] + bh2[0];
}

// ============ launch ============
extern "C" void kernel_launch(void* const* d_in, const int* in_sizes, int n_in,
                              void* d_out, int out_size, void* d_ws, size_t ws_size,
                              hipStream_t stream)
{
    const float* x   = (const float*)d_in[0];
    const int*   ei  = (const int*)d_in[1];
    const int*   bat = (const int*)d_in[2];
    const float* W1  = (const float*)d_in[3];
    const float* as1 = (const float*)d_in[4];
    const float* ad1 = (const float*)d_in[5];
    const float* b1  = (const float*)d_in[6];
    const float* W2  = (const float*)d_in[7];
    const float* as2 = (const float*)d_in[8];
    const float* ad2 = (const float*)d_in[9];
    const float* b2  = (const float*)d_in[10];
    const float* Wh1 = (const float*)d_in[11];
    const float* bh1 = (const float*)d_in[12];
    const float* Wh2 = (const float*)d_in[13];
    const float* bh2 = (const float*)d_in[14];
    float* out = (float*)d_out;

    const int N  = in_sizes[0] / 128;
    const int E  = in_sizes[1] / 2;
    const int Ep = E + N;
    const int G  = 128;

    char* w = (char*)d_ws;
    size_t off = 0;
    auto alloc = [&](size_t bytes) -> char* {
        char* p = w + off; off += (bytes + 511) & ~(size_t)511; return p;
    };
    float* agg   = (float*)alloc((size_t)N * 512 * 4);   // layer-1 aggregated x; reused as xh2
    float* h1    = (float*)alloc((size_t)N * 512 * 4);   // reused as h2
    float* As1   = (float*)alloc((size_t)N * 4 * 4);
    float* Ad1   = (float*)alloc((size_t)N * 4 * 4);
    float* As2   = (float*)alloc((size_t)N * 4);
    float* Ad2   = (float*)alloc((size_t)N * 4);
    float* w_s1  = (float*)alloc(512 * 4);
    float* w_d1  = (float*)alloc(512 * 4);
    int*   startb= (int*)alloc((size_t)(N + 1) * 4);
    int*   csr   = (int*)alloc((size_t)Ep * 4);
    int*   sums  = (int*)alloc(4096);
    int*   gstart= (int*)alloc((size_t)(G + 1) * 4);
    char* zbase = w + off;                                // zero-init group
    int*   deg    = (int*)alloc((size_t)N * 4);
    int*   cursor = (int*)alloc((size_t)N * 4);
    float* pooled = (float*)alloc((size_t)G * 128 * 4);
    size_t zbytes = (size_t)((w + off) - zbase);
    float* xh2 = agg;    // agg dead after GEMM1 (stream-ordered)
    float* h2  = h1;     // h1 dead after GEMM2

    hipMemsetAsync(zbase, 0, zbytes, stream);

    // 1) attention logits straight from x (fold att vectors through W1)
    k_wvec<<<4, 128, 0, stream>>>(W1, as1, ad1, w_s1, w_d1);
    k_attn_x<<<(N + 3) / 4, 256, 0, stream>>>(x, w_s1, w_d1, As1, Ad1, N);
    // 2) CSR by destination (self-loops appended)
    k_count<<<(Ep + 255) / 256, 256, 0, stream>>>(ei, deg, E, Ep);
    int nb = (N + 1 + 1023) / 1024;
    k_scanA<<<nb, 1024, 0, stream>>>(deg, startb, sums, N + 1, N);
    k_scanB<<<1, 64, 0, stream>>>(sums, nb);
    k_scanC<<<nb, 1024, 0, stream>>>(startb, sums, N + 1);
    k_fill<<<(Ep + 255) / 256, 256, 0, stream>>>(ei, startb, cursor, csr, E, Ep);
    // 3) graph boundaries (batch sorted)
    k_gbound<<<(N + 255) / 256, 256, 0, stream>>>(bat, gstart, N, G);
    // 4) layer-1 aggregation over raw x -> agg [N, 4*128]
    k_agg1x<<<N, 128, 0, stream>>>(startb, csr, As1, Ad1, x, agg, N);
    // 5) block-diag projection + bias + ELU (split-bf16 MFMA): h1_h = elu(agg_h @ W1_h^T + b1_h)
    k_gemm_mfma<true><<<dim3((N + 127) / 128, 1, 4), 256, 0, stream>>>(
        agg, W1, b1, h1, N, 128, 512, 128, 512, 128L, 16384L, 128L, 128L);
    // 6) xh2 = h1 @ W2^T  [N,128]  (split-bf16 MFMA)
    k_gemm_mfma<false><<<dim3((N + 127) / 128, 1, 1), 256, 0, stream>>>(
        h1, W2, nullptr, xh2, N, 512, 512, 512, 128, 0L, 0L, 0L, 0L);
    // 7) layer-2 attention logits
    k_attn2<<<(N + 3) / 4, 256, 0, stream>>>(xh2, as2, ad2, As2, Ad2, N);
    // 8) layer-2 aggregation + bias + ELU -> h2 [N,128]
    k_agg2<<<N, 128, 0, stream>>>(startb, csr, As2, Ad2, xh2, b2, h2, N);
    // 9) two-stage pooling + MLP head
    k_poolA<<<(N + PCH - 1) / PCH, 128, 0, stream>>>(h2, bat, pooled, N);
    k_head<<<G, 128, 0, stream>>>(pooled, gstart, Wh1, bh1, Wh2, bh2, out);
}